// Round 5
// baseline (243.169 us; speedup 1.0000x reference)
//
#include <hip/hip_runtime.h>
#include <stdint.h>

// Problem constants (match reference)
#define DVOL 256
#define NVOX (DVOL * DVOL * DVOL)   // 16,777,216 voxels
#define N_LABELS 1000

#define BLOCK    256
#define WAVES    4
#define TILE_VOX 256                          // voxels per wave-tile (1KB/stream)
#define ITERS    8
#define BLOCK_VOX (WAVES * ITERS * TILE_VOX)  // 8192 voxels per block
#define NBLOCKS  (NVOX / BLOCK_VOX)           // 2048 blocks

typedef float f32x4 __attribute__((ext_vector_type(4)));
typedef int   i32x4 __attribute__((ext_vector_type(4)));

// v6: wave-private double-buffered global_load_lds pipeline.
//
// Theory: every prior version held only ~2KB of reads in flight per wave
// (compiler sinks VGPR loads into the use chain — VGPR counts proved it in
// v2/v3). Little's law: 6.3 TB/s x ~1us loaded latency needs ~25KB in
// flight per CU, sustained. fillBufferAligned (same trace) proves stores
// saturate at 9% occupancy; reads are what need MLP.
//
// global_load_lds is the one load primitive the compiler can neither sink
// nor serialize (side-effecting intrinsic; m201-class kernels keep its
// prefetches in flight across counted asm waits). Each wave double-buffers
// 256-voxel tiles (1KB labels + 1KB parenchyma per tile) in its own LDS
// slice: no __syncthreads in the loop (wave-private), so no forced
// vmcnt(0) drain. 32 waves/CU x 2KB prefetch = 64KB in flight per CU.
//
// vmcnt accounting (robust to scheduler reordering because the asm
// "memory" barriers pin each iteration's window): at wait(t), ops
// provably younger than stage(t) = stores(t-1)[2] + stage(t+1)[2] = 4
//   -> steady state: s_waitcnt vmcnt(4)
//   -> t==0 (no older stores) and t==ITERS-1 (no next stage): vmcnt(2)
__device__ __forceinline__ void gl_lds16(const void* g, void* l) {
    __builtin_amdgcn_global_load_lds(
        (const __attribute__((address_space(1))) unsigned int*)g,
        (__attribute__((address_space(3))) unsigned int*)l,
        16, 0, 0);
}

__global__ __launch_bounds__(BLOCK)
void vessel_fuse_kernel(const int* __restrict__ labels,
                        const int* __restrict__ keep_mask,
                        const float* __restrict__ intensity_lut,
                        const float* __restrict__ parenchyma,
                        float* __restrict__ out,      // [NVOX] float32
                        float* __restrict__ maskf)    // [NVOX] float32 (0.0/1.0)
{
    __shared__ float s_scale[N_LABELS];
    // stage[buf][wave] = { 1KB labels | 1KB parenchyma }
    __shared__ __align__(16) unsigned char s_stage[2][WAVES][2048];

    for (int l = threadIdx.x; l < N_LABELS; l += BLOCK) {
        const bool keep = (l > 0) && (keep_mask[l] > 0);
        // Kept intensities lie in [0,0.7) u [1.3,2): never exactly 1.0,
        // so scale==1.0f exactly encodes "not a vessel".
        s_scale[l] = keep ? intensity_lut[l] : 1.0f;
    }
    __syncthreads();   // drains prologue vmem -> vmcnt==0 entering the loop

    const int wave = threadIdx.x >> 6;
    const int lane = threadIdx.x & 63;
    const int blkVox = blockIdx.x * BLOCK_VOX;

    // Prologue: stage tile 0 (lane's 16B slice; LDS dest is wave-uniform
    // base, HW adds lane*16 — layout is linear, matching consume order).
    {
        const int v0 = blkVox + wave * TILE_VOX + lane * 4;
        gl_lds16(labels + v0,     &s_stage[0][wave][0]);
        gl_lds16(parenchyma + v0, &s_stage[0][wave][1024]);
    }

#pragma unroll
    for (int t = 0; t < ITERS; ++t) {
        if (t + 1 < ITERS) {
            const int vn = blkVox + ((t + 1) * WAVES + wave) * TILE_VOX + lane * 4;
            gl_lds16(labels + vn,     &s_stage[(t + 1) & 1][wave][0]);
            gl_lds16(parenchyma + vn, &s_stage[(t + 1) & 1][wave][1024]);
        }
        if (t == 0 || t == ITERS - 1) {
            asm volatile("s_waitcnt vmcnt(2)" ::: "memory");
        } else {
            asm volatile("s_waitcnt vmcnt(4)" ::: "memory");
        }

        const i32x4 L = ((const i32x4*)&s_stage[t & 1][wave][0])[lane];
        const f32x4 P = ((const f32x4*)&s_stage[t & 1][wave][1024])[lane];

        f32x4 s, o, m;
        s.x = s_scale[L.x];
        s.y = s_scale[L.y];
        s.z = s_scale[L.z];
        s.w = s_scale[L.w];
        o.x = P.x * s.x;  m.x = (s.x != 1.0f) ? 1.0f : 0.0f;
        o.y = P.y * s.y;  m.y = (s.y != 1.0f) ? 1.0f : 0.0f;
        o.z = P.z * s.z;  m.z = (s.z != 1.0f) ? 1.0f : 0.0f;
        o.w = P.w * s.w;  m.w = (s.w != 1.0f) ? 1.0f : 0.0f;

        // float4 index of this lane's slice
        const int gi = (blkVox + (t * WAVES + wave) * TILE_VOX) / 4 + lane;
        __builtin_nontemporal_store(o, (f32x4*)out + gi);
        __builtin_nontemporal_store(m, (f32x4*)maskf + gi);
    }
}

extern "C" void kernel_launch(void* const* d_in, const int* in_sizes, int n_in,
                              void* d_out, int out_size, void* d_ws, size_t ws_size,
                              hipStream_t stream) {
    (void)in_sizes; (void)n_in; (void)d_ws; (void)ws_size; (void)out_size;

    const int*   vessel_labels = (const int*)d_in[0];   // [D,D,D] int32
    const int*   keep_mask     = (const int*)d_in[1];   // [N_LABELS] int32
    const float* intensity_lut = (const float*)d_in[2]; // [N_LABELS] float32
    const float* parenchyma    = (const float*)d_in[3]; // [D,D,D] float32

    float* out   = (float*)d_out;          // output 0: modulated parenchyma
    float* maskf = (float*)d_out + NVOX;   // output 1: vessel mask as float

    vessel_fuse_kernel<<<NBLOCKS, BLOCK, 0, stream>>>(
        vessel_labels, keep_mask, intensity_lut, parenchyma, out, maskf);
}